// Round 12
// baseline (44.650 us; speedup 1.0000x reference)
//
#include <hip/hip_runtime.h>

#define BB 8
#define NN 2048
#define TT 64
#define DD 256
#define KK 128

// ---- per-batch counting-sort grid (built once by prep, queried by detect) ----
#define GSZ 16
#define NC (GSZ * GSZ * GSZ)   // 4096 = 512*8 (scan: 8 cells/thread)
#define DTHR 0.053f     // conservative per-dim candidate radius (covers fp error)
#define D2THR 0.0025f   // sqrt(max(d2,0)) < 0.05  <=>  d2 < 0.0025 (exact)
#define GG 2            // detect chunks per (b,t)

// ---- workspace layout (bytes) ----
#define WS_COUNTS 0                       // 512 ints
#define WS_PLANES 2048                    // 512*5 floats
#define WS_GRIDP  12288                   // 8 * 8 floats {og[3],h[3],pad}
#define WS_GOFS   12544                   // 8 * 4096 u16 (end offsets) = 64 KB
#define WS_GSP    78080                   // 8 * 2048 float4 (sorted points)
#define WS_NEEDED (WS_GSP + BB * NN * 16)

// ---------------------------------------------------------------------------
// prep: one block per batch. Builds the cell-sorted point array + u16
// end-offset table + grid params; zeroes counts. min/max bbox is EXACT
// (order-free); cell assignment identical expression -> per-cell multiset
// identical to r10's in-block build => downstream counts bit-identical.
// ---------------------------------------------------------------------------
__global__ __launch_bounds__(512) void prep_kernel(
    const float* __restrict__ points, float* __restrict__ gridp,
    unsigned short* __restrict__ gofs, float4* __restrict__ gsp,
    int* __restrict__ counts)
{
#pragma clang fp contract(off)
    __shared__ float4 sp[NN];        // 32 KB cell-sorted {x,y,z,||p||^2}
    __shared__ int    cellofs[NC];   // 16 KB
    __shared__ float  sred[8][6];
    __shared__ int    swsum[8];

    const int tid  = threadIdx.x;
    const int lane = tid & 63;
    const int wav  = tid >> 6;
    const int b    = blockIdx.x;

    if (tid < TT) counts[b * TT + tid] = 0;

    const float* P = points + (size_t)b * NN * 3;

    // ---- vectorized stage: thread t owns points 4t..4t+3 via 3 float4 ----
    const float4* P4 = (const float4*)P;
    const float4 A  = P4[tid * 3 + 0];
    const float4 Bv = P4[tid * 3 + 1];
    const float4 C  = P4[tid * 3 + 2];
    float px[4], py[4], pz[4], ps[4];
    px[0] = A.x;  py[0] = A.y;  pz[0] = A.z;
    px[1] = A.w;  py[1] = Bv.x; pz[1] = Bv.y;
    px[2] = Bv.z; py[2] = Bv.w; pz[2] = C.x;
    px[3] = C.y;  py[3] = C.z;  pz[3] = C.w;

    float mnx = 3.4e38f, mny = 3.4e38f, mnz = 3.4e38f;
    float mxx = -3.4e38f, mxy = -3.4e38f, mxz = -3.4e38f;
#pragma unroll
    for (int k = 0; k < 4; ++k) {
        ps[k] = (px[k] * px[k] + py[k] * py[k]) + pz[k] * pz[k]; // pts_sq order
        mnx = fminf(mnx, px[k]); mxx = fmaxf(mxx, px[k]);
        mny = fminf(mny, py[k]); mxy = fmaxf(mxy, py[k]);
        mnz = fminf(mnz, pz[k]); mxz = fmaxf(mxz, pz[k]);
    }
#pragma unroll
    for (int o = 32; o > 0; o >>= 1) {
        mnx = fminf(mnx, __shfl_xor(mnx, o));
        mny = fminf(mny, __shfl_xor(mny, o));
        mnz = fminf(mnz, __shfl_xor(mnz, o));
        mxx = fmaxf(mxx, __shfl_xor(mxx, o));
        mxy = fmaxf(mxy, __shfl_xor(mxy, o));
        mxz = fmaxf(mxz, __shfl_xor(mxz, o));
    }
    if (lane == 0) {
        sred[wav][0] = mnx; sred[wav][1] = mny; sred[wav][2] = mnz;
        sred[wav][3] = mxx; sred[wav][4] = mxy; sred[wav][5] = mxz;
    }
    for (int c = tid; c < NC; c += 512) cellofs[c] = 0;
    __syncthreads();

    // grid params (min/max exact under any order)
    float a0 = sred[0][0], a1 = sred[0][1], a2 = sred[0][2];
    float m3 = sred[0][3], m4 = sred[0][4], m5 = sred[0][5];
#pragma unroll
    for (int w = 1; w < 8; ++w) {
        a0 = fminf(a0, sred[w][0]); a1 = fminf(a1, sred[w][1]); a2 = fminf(a2, sred[w][2]);
        m3 = fmaxf(m3, sred[w][3]); m4 = fmaxf(m4, sred[w][4]); m5 = fmaxf(m5, sred[w][5]);
    }
    const float ogx = a0 - 1e-3f, ogy = a1 - 1e-3f, ogz = a2 - 1e-3f;
    const float hx = fmaxf((m3 - ogx) * (1.0f / 15.9f), 0.06f);
    const float hy = fmaxf((m4 - ogy) * (1.0f / 15.9f), 0.06f);
    const float hz = fmaxf((m5 - ogz) * (1.0f / 15.9f), 0.06f);
    const float ivx = 1.0f / hx, ivy = 1.0f / hy, ivz = 1.0f / hz;
    if (tid == 0) {
        float* g = gridp + b * 8;
        g[0] = ogx; g[1] = ogy; g[2] = ogz;
        g[3] = hx;  g[4] = hy;  g[5] = hz;
    }

    // histogram
    int cell[4];
#pragma unroll
    for (int k = 0; k < 4; ++k) {
        int cx = (int)floorf((px[k] - ogx) * ivx);
        int cy = (int)floorf((py[k] - ogy) * ivy);
        int cz = (int)floorf((pz[k] - ogz) * ivz);
        cx = min(GSZ - 1, max(0, cx));
        cy = min(GSZ - 1, max(0, cy));
        cz = min(GSZ - 1, max(0, cz));
        cell[k] = (cz * GSZ + cy) * GSZ + cx;
        atomicAdd(&cellofs[cell[k]], 1);
    }
    __syncthreads();

    // exclusive prefix sum over NC=4096 cells (8 per thread)
    const int base = tid * 8;
    int loc[8];
    int tsum = 0;
#pragma unroll
    for (int k = 0; k < 8; ++k) { loc[k] = tsum; tsum += cellofs[base + k]; }
    int inc = tsum;
#pragma unroll
    for (int o = 1; o < 64; o <<= 1) {
        const int v = __shfl_up(inc, o);
        if (lane >= o) inc += v;
    }
    if (lane == 63) swsum[wav] = inc;
    __syncthreads();
    int wbase = 0;
    for (int w = 0; w < wav; ++w) wbase += swsum[w];
    const int texcl = (inc - tsum) + wbase;
#pragma unroll
    for (int k = 0; k < 8; ++k) cellofs[base + k] = texcl + loc[k];
    __syncthreads();

    // scatter: cellofs[c] becomes END offset after all inserts
#pragma unroll
    for (int k = 0; k < 4; ++k) {
        const int pos = atomicAdd(&cellofs[cell[k]], 1);
        sp[pos] = make_float4(px[k], py[k], pz[k], ps[k]);
    }
    __syncthreads();

    // store sorted points (coalesced) + end offsets packed to u16
#pragma unroll
    for (int k = 0; k < 4; ++k) {
        const int j = tid + k * 512;
        gsp[b * NN + j] = sp[j];
    }
    uint4 w;
    w.x = (unsigned)cellofs[base + 0] | ((unsigned)cellofs[base + 1] << 16);
    w.y = (unsigned)cellofs[base + 2] | ((unsigned)cellofs[base + 3] << 16);
    w.z = (unsigned)cellofs[base + 4] | ((unsigned)cellofs[base + 5] << 16);
    w.w = (unsigned)cellofs[base + 6] | ((unsigned)cellofs[base + 7] << 16);
    ((uint4*)(gofs + b * NC))[tid] = w;
}

// ---------------------------------------------------------------------------
// detect: GG blocks per (b,t); each handles 1024 of the 2048 queries.
// Bulk-loads the prebuilt sorted grid into 40 KB LDS (4 blocks/CU), then the
// validated query: reflect, +-1 window as x-range scans, exact
// d2 = (rsq+pts_sq) - dot(2r,p) < 0.0025f (bit-identical r2-r11).
// ---------------------------------------------------------------------------
__global__ __launch_bounds__(512) void detect_kernel(
    const float* __restrict__ points, const int* __restrict__ sample_idx,
    const float* __restrict__ z_local, const float* __restrict__ gridp,
    const unsigned short* __restrict__ gofs, const float4* __restrict__ gsp,
    int* __restrict__ counts, float* __restrict__ planes,
    float* __restrict__ out)
{
#pragma clang fp contract(off)
    __shared__ float4 sp[NN];                         // 32 KB
    __shared__ __align__(16) unsigned short cellofs[NC]; // 8 KB (end offsets)
    __shared__ int blk_cnt;

    const int tid   = threadIdx.x;
    const int lane  = tid & 63;
    const int blk   = blockIdx.x;
    const int bt    = blk / GG;
    const int chunk = blk % GG;
    const int b     = bt / TT;

    if (tid == 0) blk_cnt = 0;

    const float* P = points + (size_t)b * NN * 3;

    // grid params (uniform broadcast loads)
    const float* g = gridp + b * 8;
    const float ogx = g[0], ogy = g[1], ogz = g[2];
    const float hx = g[3], hy = g[4], hz = g[5];
    const float ivx = 1.0f / hx, ivy = 1.0f / hy, ivz = 1.0f / hz;

    // candidate plane — exact reference ops
    const int i1 = sample_idx[bt * 2 + 0];
    const int i2 = sample_idx[bt * 2 + 1];
    const float q1x = P[i1 * 3 + 0], q1y = P[i1 * 3 + 1], q1z = P[i1 * 3 + 2];
    const float q2x = P[i2 * 3 + 0], q2y = P[i2 * 3 + 1], q2z = P[i2 * 3 + 2];
    const float dx0 = q2x - q1x, dy0 = q2y - q1y, dz0 = q2z - q1z;
    const float nd  = sqrtf((dx0 * dx0 + dy0 * dy0) + dz0 * dz0);
    const float den = nd + 1e-12f;
    const float nx = dx0 / den, ny = dy0 / den, nz = dz0 / den;
    const float e0 = (nx * (q1x + q2x)) * 0.5f;
    const float e1 = (ny * (q1y + q2y)) * 0.5f;
    const float e2 = (nz * (q1z + q2z)) * 0.5f;
    const float off = (e0 + e1) + e2;
    const float nnorm = sqrtf((nx * nx + ny * ny) + nz * nz);
    const float nden  = nnorm + 1e-12f;
    const float nnx = nx / nden, nny = ny / nden, nnz = nz / nden;

    // z_local passthrough slice: 65536 float4 / 1024 blocks = 64 each
    if (tid < 64) {
        const float4* zl = (const float4*)z_local;
        float4* zo = (float4*)(out + BB * DD);
        zo[blk * 64 + tid] = zl[blk * 64 + tid];
    }

    // bulk-load prebuilt grid into LDS (coalesced)
#pragma unroll
    for (int k = 0; k < 4; ++k) {
        const int j = tid + k * 512;
        sp[j] = gsp[b * NN + j];
    }
    ((uint4*)cellofs)[tid] = ((const uint4*)(gofs + b * NC))[tid];
    __syncthreads();

    // queries in SORTED order: reflect + range-scan exact NN match
    int cnt = 0;
#pragma unroll
    for (int k = 0; k < 2; ++k) {
        const int n = chunk * (NN / GG) + tid + k * 512;
        const float4 q = sp[n];        // sorted: adjacent lanes share cells
        const float sd = ((q.x * nnx + q.y * nny) + q.z * nnz) - off;
        const float s  = 2.0f * sd;
        const float rx = q.x - s * nnx;
        const float ry = q.y - s * nny;
        const float rz = q.z - s * nnz;
        const float rsq = (rx * rx + ry * ry) + rz * rz;
        const float r2x = rx + rx, r2y = ry + ry, r2z = rz + rz; // exact *2

        const float tx = rx - ogx; const float cfx = floorf(tx * ivx);
        const float ty = ry - ogy; const float cfy = floorf(ty * ivy);
        const float tz = rz - ogz; const float cfz = floorf(tz * ivz);
        const int cxi = (int)cfx, cyi = (int)cfy, czi = (int)cfz;
        const float fx = tx - cfx * hx;
        const float fy = ty - cfy * hy;
        const float fz = tz - cfz * hz;
        const int cx0 = max(0, cxi + ((fx < DTHR) ? -1 : 0));
        const int cx1 = min(GSZ - 1, cxi + ((fx > hx - DTHR) ? 1 : 0));
        const int ly = (fy < DTHR) ? -1 : 0, uy = (fy > hy - DTHR) ? 1 : 0;
        const int lz = (fz < DTHR) ? -1 : 0, uz = (fz > hz - DTHR) ? 1 : 0;

        int matched = 0;
        if (cx0 <= cx1) {
            for (int dz = lz; dz <= uz; ++dz) {
                const int cz = czi + dz; if ((unsigned)cz >= GSZ) continue;
                for (int dy = ly; dy <= uy; ++dy) {
                    const int cy = cyi + dy; if ((unsigned)cy >= GSZ) continue;
                    const int rowbase = (cz * GSZ + cy) * GSZ;
                    const int idx0 = rowbase + cx0;
                    const int idx1 = rowbase + cx1;
                    const int jb = (idx0 == 0) ? 0 : (int)cellofs[idx0 - 1];
                    const int je = (int)cellofs[idx1];
                    for (int j = jb; j < je; ++j) {
                        const float4 pm = sp[j];
                        const float c2 = (r2x * pm.x + r2y * pm.y) + r2z * pm.z;
                        const float t1 = rsq + pm.w;
                        matched |= ((t1 - c2) < D2THR) ? 1 : 0;
                    }
                }
            }
        }
        cnt += matched;
    }

    for (int o = 32; o > 0; o >>= 1) cnt += __shfl_down(cnt, o);
    if (lane == 0) atomicAdd(&blk_cnt, cnt);
    __syncthreads();

    if (tid == 0) {
        atomicAdd(&counts[bt], blk_cnt);
        if (chunk == 0) {
            planes[bt * 5 + 0] = nx;
            planes[bt * 5 + 1] = ny;
            planes[bt * 5 + 2] = nz;
            planes[bt * 5 + 3] = off;
            planes[bt * 5 + 4] = nd;
        }
    }
}

// ---------------------------------------------------------------------------
// finalize: per-batch parallel argmax + centroid + float4 GEMV (r10-proven).
// ---------------------------------------------------------------------------
__global__ __launch_bounds__(256) void finalize_kernel(
    const float* __restrict__ points, const float* __restrict__ z_enc,
    const float* __restrict__ Wm, const float* __restrict__ bias,
    const int* __restrict__ counts, const float* __restrict__ planes,
    float* __restrict__ out)
{
    const int b = blockIdx.x, tid = threadIdx.x;
    const int lane = tid & 63, wav = tid >> 6;
    __shared__ __align__(16) float zaug[DD + 4];
    __shared__ float swc[4][3];
    __shared__ float sbest[5];

    const float* P = points + (size_t)b * NN * 3;
    float sx = 0.f, sy = 0.f, sz = 0.f;
#pragma unroll
    for (int k = 0; k < 8; ++k) {
        const int j = tid + k * 256;
        sx += P[j * 3 + 0]; sy += P[j * 3 + 1]; sz += P[j * 3 + 2];
    }
#pragma unroll
    for (int o = 32; o > 0; o >>= 1) {
        sx += __shfl_xor(sx, o); sy += __shfl_xor(sy, o); sz += __shfl_xor(sz, o);
    }
    if (lane == 0) { swc[wav][0] = sx; swc[wav][1] = sy; swc[wav][2] = sz; }

    zaug[tid] = z_enc[b * DD + tid];

    if (wav == 0) {
        const int bt = b * TT + lane;
        const float p0 = planes[bt * 5 + 0];
        const float p1 = planes[bt * 5 + 1];
        const float p2 = planes[bt * 5 + 2];
        const float p3 = planes[bt * 5 + 3];
        const float ndv = planes[bt * 5 + 4];
        const int   c  = counts[bt];
        const float frac = (ndv < 1e-8f) ? -1.0f : (float)c * (1.0f / 2048.0f);
        float m = frac;
#pragma unroll
        for (int o = 32; o > 0; o >>= 1) m = fmaxf(m, __shfl_xor(m, o));
        const unsigned long long win = __ballot(frac == m);
        const int first = __ffsll(win) - 1;   // smallest t among maxima
        const float w0 = __shfl(p0, first);
        const float w1 = __shfl(p1, first);
        const float w2 = __shfl(p2, first);
        const float w3 = __shfl(p3, first);
        if (lane == 0) {
            if (m > 0.0f) {
                sbest[0] = w0; sbest[1] = w1; sbest[2] = w2; sbest[3] = w3; sbest[4] = m;
            } else {
                sbest[0] = 0.f; sbest[1] = 1.f; sbest[2] = 0.f; sbest[3] = 0.f; sbest[4] = 0.f;
            }
        }
    }
    __syncthreads();

    if (tid == 0) {
        const float cx = (((swc[0][0] + swc[1][0]) + swc[2][0]) + swc[3][0]) / (float)NN;
        const float cy = (((swc[0][1] + swc[1][1]) + swc[2][1]) + swc[3][1]) / (float)NN;
        const float cz = (((swc[0][2] + swc[1][2]) + swc[2][2]) + swc[3][2]) / (float)NN;
        const float bn0 = sbest[0], bn1 = sbest[1], bn2 = sbest[2];
        const float bo = sbest[3], bc = sbest[4];
        const float sd = ((bn0 * cx + bn1 * cy) + bn2 * cz) - bo;
        zaug[DD + 0] = bn0; zaug[DD + 1] = bn1; zaug[DD + 2] = bn2; zaug[DD + 3] = sd;
        float* normals = out + (BB * DD + BB * KK * DD);
        normals[b * 3 + 0] = bn0; normals[b * 3 + 1] = bn1; normals[b * 3 + 2] = bn2;
        float* offs = normals + BB * 3;
        offs[b] = bo;
        float* conf = offs + BB;
        conf[b] = bc;
    }
    __syncthreads();

    const float4* wrow4 = (const float4*)(Wm + (size_t)tid * (DD + 4));
    const float4* z4 = (const float4*)zaug;
    float acc = bias[tid];
#pragma unroll 4
    for (int v = 0; v < (DD + 4) / 4; ++v) {
        const float4 wv = wrow4[v];
        const float4 zv = z4[v];
        acc += zv.x * wv.x;
        acc += zv.y * wv.y;
        acc += zv.z * wv.z;
        acc += zv.w * wv.w;
    }
    out[b * DD + tid] = acc;
}

extern "C" void kernel_launch(void* const* d_in, const int* in_sizes, int n_in,
                              void* d_out, int out_size, void* d_ws, size_t ws_size,
                              hipStream_t stream) {
    const float* points     = (const float*)d_in[0];
    const float* z_enc      = (const float*)d_in[1];
    const float* z_local    = (const float*)d_in[2];
    // d_in[3] = proxy_coords (unused by reference outputs)
    const int*   sample_idx = (const int*)d_in[4];
    const float* Wm         = (const float*)d_in[5];
    const float* bias       = (const float*)d_in[6];
    float* out = (float*)d_out;

    char* wsb = (char*)d_ws;
    int*            counts = (int*)(wsb + WS_COUNTS);
    float*          planes = (float*)(wsb + WS_PLANES);
    float*          gridp  = (float*)(wsb + WS_GRIDP);
    unsigned short* gofs   = (unsigned short*)(wsb + WS_GOFS);
    float4*         gsp    = (float4*)(wsb + WS_GSP);

    prep_kernel<<<BB, 512, 0, stream>>>(points, gridp, gofs, gsp, counts);
    detect_kernel<<<BB * TT * GG, 512, 0, stream>>>(
        points, sample_idx, z_local, gridp, gofs, gsp, counts, planes, out);
    finalize_kernel<<<BB, 256, 0, stream>>>(
        points, z_enc, Wm, bias, counts, planes, out);
}

// Round 15
// 39.414 us; speedup vs baseline: 1.1328x; 1.1328x over previous
//
#include <hip/hip_runtime.h>

#define BB 8
#define NN 2048
#define TT 64
#define DD 256
#define KK 128

// ---- per-block LDS counting-sort grid ----
#define GSZ 16
#define NC (GSZ * GSZ * GSZ)
#define DTHR 0.053f     // conservative per-dim candidate radius (covers fp error)
#define D2THR 0.0025f   // sqrt(max(d2,0)) < 0.05  <=>  d2 < 0.0025 (exact)

// ---------------------------------------------------------------------------
// One block per (b,t). Counting-sort LDS grid + sorted-order queries.
// Numerics bit-identical to reference (validated r2-r12):
//   d2 = (rsq + pts_sq) - dot(2r, p), non-FMA, left-assoc; d2 < 0.0025f.
// This is the best-measured configuration (39.7 us, round 8) restored
// verbatim after two fused-kernel correctness failures (r13/r14): the
// kernel boundary is the only verified cross-XCD publication mechanism.
// ---------------------------------------------------------------------------
__global__ __launch_bounds__(512) void detect_kernel(
    const float* __restrict__ points, const int* __restrict__ sample_idx,
    const float* __restrict__ z_local,
    int* __restrict__ counts, float* __restrict__ planes,
    float* __restrict__ out)
{
#pragma clang fp contract(off)
    __shared__ float4 sp[NN];        // 32 KB cell-sorted {x,y,z,||p||^2}
    __shared__ int    cellofs[NC];   // 16 KB: hist -> excl start -> end offset
    __shared__ float  sred[8][6];
    __shared__ int    swsum[8];
    __shared__ float  g[6];          // org[3], h[3]
    __shared__ int    blk_cnt;

    const int tid  = threadIdx.x;
    const int lane = tid & 63;
    const int wav  = tid >> 6;
    const int bt   = blockIdx.x;
    const int b    = bt / TT;

    if (tid == 0) blk_cnt = 0;

    const float* P = points + (size_t)b * NN * 3;

    // ---- candidate plane (hoisted: loads overlap staging) ----
    const int i1 = sample_idx[bt * 2 + 0];
    const int i2 = sample_idx[bt * 2 + 1];
    const float q1x = P[i1 * 3 + 0], q1y = P[i1 * 3 + 1], q1z = P[i1 * 3 + 2];
    const float q2x = P[i2 * 3 + 0], q2y = P[i2 * 3 + 1], q2z = P[i2 * 3 + 2];
    const float dx0 = q2x - q1x, dy0 = q2y - q1y, dz0 = q2z - q1z;
    const float nd  = sqrtf((dx0 * dx0 + dy0 * dy0) + dz0 * dz0);
    const float den = nd + 1e-12f;
    const float nx = dx0 / den, ny = dy0 / den, nz = dz0 / den;
    const float e0 = (nx * (q1x + q2x)) * 0.5f;
    const float e1 = (ny * (q1y + q2y)) * 0.5f;
    const float e2 = (nz * (q1z + q2z)) * 0.5f;
    const float off = (e0 + e1) + e2;
    const float nnorm = sqrtf((nx * nx + ny * ny) + nz * nz);
    const float nden  = nnorm + 1e-12f;
    const float nnx = nx / nden, nny = ny / nden, nnz = nz / nden;

    // z_local passthrough slice: 65536 float4 total / 512 blocks = 128 each
    if (tid < 128) {
        const float4* zl = (const float4*)z_local;
        float4* zo = (float4*)(out + BB * DD);
        zo[bt * 128 + tid] = zl[bt * 128 + tid];
    }

    // ---- load 4 points/thread to registers + bbox ----
    float px[4], py[4], pz[4], ps[4];
    float mnx = 3.4e38f, mny = 3.4e38f, mnz = 3.4e38f;
    float mxx = -3.4e38f, mxy = -3.4e38f, mxz = -3.4e38f;
#pragma unroll
    for (int k = 0; k < 4; ++k) {
        const int j = tid + k * 512;
        const float x = P[j * 3 + 0], y = P[j * 3 + 1], z = P[j * 3 + 2];
        px[k] = x; py[k] = y; pz[k] = z;
        ps[k] = (x * x + y * y) + z * z;   // matches pts_sq op order
        mnx = fminf(mnx, x); mxx = fmaxf(mxx, x);
        mny = fminf(mny, y); mxy = fmaxf(mxy, y);
        mnz = fminf(mnz, z); mxz = fmaxf(mxz, z);
    }
#pragma unroll
    for (int o = 32; o > 0; o >>= 1) {
        mnx = fminf(mnx, __shfl_xor(mnx, o));
        mny = fminf(mny, __shfl_xor(mny, o));
        mnz = fminf(mnz, __shfl_xor(mnz, o));
        mxx = fmaxf(mxx, __shfl_xor(mxx, o));
        mxy = fmaxf(mxy, __shfl_xor(mxy, o));
        mxz = fmaxf(mxz, __shfl_xor(mxz, o));
    }
    if (lane == 0) {
        sred[wav][0] = mnx; sred[wav][1] = mny; sred[wav][2] = mnz;
        sred[wav][3] = mxx; sred[wav][4] = mxy; sred[wav][5] = mxz;
    }
    // zero histogram (independent of the reduction)
    for (int c = tid; c < NC; c += 512) cellofs[c] = 0;
    __syncthreads();

    if (tid == 0) {
        float a0 = sred[0][0], a1 = sred[0][1], a2 = sred[0][2];
        float m3 = sred[0][3], m4 = sred[0][4], m5 = sred[0][5];
        for (int w = 1; w < 8; ++w) {
            a0 = fminf(a0, sred[w][0]); a1 = fminf(a1, sred[w][1]); a2 = fminf(a2, sred[w][2]);
            m3 = fmaxf(m3, sred[w][3]); m4 = fmaxf(m4, sred[w][4]); m5 = fmaxf(m5, sred[w][5]);
        }
        g[0] = a0 - 1e-3f; g[1] = a1 - 1e-3f; g[2] = a2 - 1e-3f;
        g[3] = fmaxf((m3 - g[0]) * (1.0f / 15.9f), 0.06f);
        g[4] = fmaxf((m4 - g[1]) * (1.0f / 15.9f), 0.06f);
        g[5] = fmaxf((m5 - g[2]) * (1.0f / 15.9f), 0.06f);
    }
    __syncthreads();
    const float ogx = g[0], ogy = g[1], ogz = g[2];
    const float hx = g[3], hy = g[4], hz = g[5];
    const float ivx = 1.0f / hx, ivy = 1.0f / hy, ivz = 1.0f / hz;

    // ---- histogram ----
    int cell[4];
#pragma unroll
    for (int k = 0; k < 4; ++k) {
        int cx = (int)floorf((px[k] - ogx) * ivx);
        int cy = (int)floorf((py[k] - ogy) * ivy);
        int cz = (int)floorf((pz[k] - ogz) * ivz);
        cx = min(GSZ - 1, max(0, cx));
        cy = min(GSZ - 1, max(0, cy));
        cz = min(GSZ - 1, max(0, cz));
        cell[k] = (cz * GSZ + cy) * GSZ + cx;
        atomicAdd(&cellofs[cell[k]], 1);
    }
    __syncthreads();

    // ---- exclusive prefix sum over NC=4096 cells (8 per thread) ----
    const int base = tid * 8;
    int loc[8];
    int tsum = 0;
#pragma unroll
    for (int k = 0; k < 8; ++k) {
        loc[k] = tsum;                 // thread-local exclusive
        tsum += cellofs[base + k];
    }
    int inc = tsum;                    // inclusive wave scan of thread sums
#pragma unroll
    for (int o = 1; o < 64; o <<= 1) {
        const int v = __shfl_up(inc, o);
        if (lane >= o) inc += v;
    }
    if (lane == 63) swsum[wav] = inc;
    __syncthreads();
    // redundant per-thread prefix over the 8 wave totals (saves a barrier)
    int wbase = 0;
    for (int w = 0; w < wav; ++w) wbase += swsum[w];
    const int texcl = (inc - tsum) + wbase;   // exclusive over threads
#pragma unroll
    for (int k = 0; k < 8; ++k) cellofs[base + k] = texcl + loc[k];  // excl starts
    __syncthreads();

    // ---- scatter: cellofs[c] becomes END offset after all inserts ----
#pragma unroll
    for (int k = 0; k < 4; ++k) {
        const int pos = atomicAdd(&cellofs[cell[k]], 1);
        sp[pos] = make_float4(px[k], py[k], pz[k], ps[k]);
    }
    __syncthreads();   // sorted grid complete

    // ---- queries in SORTED order: reflect + range-scan exact NN match ----
    int cnt = 0;
#pragma unroll
    for (int k = 0; k < 4; ++k) {
        const int n = tid + k * 512;
        const float4 q = sp[n];        // sorted: adjacent lanes share cells
        const float sd = ((q.x * nnx + q.y * nny) + q.z * nnz) - off;
        const float s  = 2.0f * sd;
        const float rx = q.x - s * nnx;
        const float ry = q.y - s * nny;
        const float rz = q.z - s * nnz;
        const float rsq = (rx * rx + ry * ry) + rz * rz;
        const float r2x = rx + rx, r2y = ry + ry, r2z = rz + rz; // exact *2

        const float tx = rx - ogx; const float cfx = floorf(tx * ivx);
        const float ty = ry - ogy; const float cfy = floorf(ty * ivy);
        const float tz = rz - ogz; const float cfz = floorf(tz * ivz);
        const int cxi = (int)cfx, cyi = (int)cfy, czi = (int)cfz;
        const float fx = tx - cfx * hx;
        const float fy = ty - cfy * hy;
        const float fz = tz - cfz * hz;
        // x-window as one contiguous cell-index range
        const int cx0 = max(0, cxi + ((fx < DTHR) ? -1 : 0));
        const int cx1 = min(GSZ - 1, cxi + ((fx > hx - DTHR) ? 1 : 0));
        const int ly = (fy < DTHR) ? -1 : 0, uy = (fy > hy - DTHR) ? 1 : 0;
        const int lz = (fz < DTHR) ? -1 : 0, uz = (fz > hz - DTHR) ? 1 : 0;

        int matched = 0;
        if (cx0 <= cx1) {
            for (int dz = lz; dz <= uz; ++dz) {
                const int cz = czi + dz; if ((unsigned)cz >= GSZ) continue;
                for (int dy = ly; dy <= uy; ++dy) {
                    const int cy = cyi + dy; if ((unsigned)cy >= GSZ) continue;
                    const int rowbase = (cz * GSZ + cy) * GSZ;
                    const int idx0 = rowbase + cx0;
                    const int idx1 = rowbase + cx1;
                    const int jb = (idx0 == 0) ? 0 : cellofs[idx0 - 1];
                    const int je = cellofs[idx1];
                    for (int j = jb; j < je; ++j) {
                        const float4 pm = sp[j];
                        const float c2 = (r2x * pm.x + r2y * pm.y) + r2z * pm.z;
                        const float t1 = rsq + pm.w;
                        matched |= ((t1 - c2) < D2THR) ? 1 : 0;
                    }
                }
            }
        }
        cnt += matched;
    }

    for (int o = 32; o > 0; o >>= 1) cnt += __shfl_down(cnt, o);
    if (lane == 0) atomicAdd(&blk_cnt, cnt);
    __syncthreads();

    if (tid == 0) {
        counts[bt] = blk_cnt;
        planes[bt * 5 + 0] = nx;
        planes[bt * 5 + 1] = ny;
        planes[bt * 5 + 2] = nz;
        planes[bt * 5 + 3] = off;
        planes[bt * 5 + 4] = nd;
    }
}

// ---------------------------------------------------------------------------
// Kernel 2: per-batch finalize:
//   wave 0: 64 lanes load (count, plane) in ONE latency round; exact argmax
//           (frac = count/2048 exact; max + first-wins via ballot/ffs; winner
//            fields broadcast via shfl).
//   all waves: centroid via shfl partials. Then GEMV.
// ---------------------------------------------------------------------------
__global__ __launch_bounds__(256) void finalize_kernel(
    const float* __restrict__ points, const float* __restrict__ z_enc,
    const float* __restrict__ Wm, const float* __restrict__ bias,
    const int* __restrict__ counts, const float* __restrict__ planes,
    float* __restrict__ out)
{
    const int b = blockIdx.x, tid = threadIdx.x;
    const int lane = tid & 63, wav = tid >> 6;
    __shared__ float zaug[DD + 4];
    __shared__ float swc[4][3];
    __shared__ float sbest[5];

    // centroid partials: 8 pts per thread, wave shfl reduce
    const float* P = points + (size_t)b * NN * 3;
    float sx = 0.f, sy = 0.f, sz = 0.f;
#pragma unroll
    for (int k = 0; k < 8; ++k) {
        const int j = tid + k * 256;
        sx += P[j * 3 + 0]; sy += P[j * 3 + 1]; sz += P[j * 3 + 2];
    }
#pragma unroll
    for (int o = 32; o > 0; o >>= 1) {
        sx += __shfl_xor(sx, o); sy += __shfl_xor(sy, o); sz += __shfl_xor(sz, o);
    }
    if (lane == 0) { swc[wav][0] = sx; swc[wav][1] = sy; swc[wav][2] = sz; }

    zaug[tid] = z_enc[b * DD + tid];

    // wave 0: parallel argmax over the 64 candidates
    if (wav == 0) {
        const int bt = b * TT + lane;
        const float p0 = planes[bt * 5 + 0];
        const float p1 = planes[bt * 5 + 1];
        const float p2 = planes[bt * 5 + 2];
        const float p3 = planes[bt * 5 + 3];
        const float ndv = planes[bt * 5 + 4];
        const int   c  = counts[bt];
        // frac exact: count*(1/2048) with count <= 2^11 -> exact float
        const float frac = (ndv < 1e-8f) ? -1.0f : (float)c * (1.0f / 2048.0f);
        float m = frac;
#pragma unroll
        for (int o = 32; o > 0; o >>= 1) m = fmaxf(m, __shfl_xor(m, o));
        const unsigned long long win = __ballot(frac == m);
        const int first = __ffsll(win) - 1;   // smallest t among maxima
        const float w0 = __shfl(p0, first);
        const float w1 = __shfl(p1, first);
        const float w2 = __shfl(p2, first);
        const float w3 = __shfl(p3, first);
        if (lane == 0) {
            if (m > 0.0f) {
                sbest[0] = w0; sbest[1] = w1; sbest[2] = w2; sbest[3] = w3; sbest[4] = m;
            } else {
                sbest[0] = 0.f; sbest[1] = 1.f; sbest[2] = 0.f; sbest[3] = 0.f; sbest[4] = 0.f;
            }
        }
    }
    __syncthreads();

    if (tid == 0) {
        const float cx = (((swc[0][0] + swc[1][0]) + swc[2][0]) + swc[3][0]) / (float)NN;
        const float cy = (((swc[0][1] + swc[1][1]) + swc[2][1]) + swc[3][1]) / (float)NN;
        const float cz = (((swc[0][2] + swc[1][2]) + swc[2][2]) + swc[3][2]) / (float)NN;
        const float bn0 = sbest[0], bn1 = sbest[1], bn2 = sbest[2];
        const float bo = sbest[3], bc = sbest[4];
        const float sd = ((bn0 * cx + bn1 * cy) + bn2 * cz) - bo;
        zaug[DD + 0] = bn0; zaug[DD + 1] = bn1; zaug[DD + 2] = bn2; zaug[DD + 3] = sd;
        float* normals = out + (BB * DD + BB * KK * DD);
        normals[b * 3 + 0] = bn0; normals[b * 3 + 1] = bn1; normals[b * 3 + 2] = bn2;
        float* offs = normals + BB * 3;
        offs[b] = bo;
        float* conf = offs + BB;
        conf[b] = bc;
    }
    __syncthreads();

    // GEMV: out[b][d] = bias[d] + sum_j zaug[j] * W[d][j]
    const float* wrow = Wm + (size_t)tid * (DD + 4);
    float acc = bias[tid];
    for (int j = 0; j < DD + 4; ++j) acc += zaug[j] * wrow[j];
    out[b * DD + tid] = acc;
}

extern "C" void kernel_launch(void* const* d_in, const int* in_sizes, int n_in,
                              void* d_out, int out_size, void* d_ws, size_t ws_size,
                              hipStream_t stream) {
    const float* points     = (const float*)d_in[0];
    const float* z_enc      = (const float*)d_in[1];
    const float* z_local    = (const float*)d_in[2];
    // d_in[3] = proxy_coords (unused by reference outputs)
    const int*   sample_idx = (const int*)d_in[4];
    const float* Wm         = (const float*)d_in[5];
    const float* bias       = (const float*)d_in[6];
    float* out = (float*)d_out;

    char* wsb = (char*)d_ws;
    int*   counts = (int*)(wsb + 0);                 // BB*TT ints
    float* planes = (float*)(wsb + BB * TT * 4);     // BB*TT*5 floats

    detect_kernel<<<BB * TT, 512, 0, stream>>>(
        points, sample_idx, z_local, counts, planes, out);
    finalize_kernel<<<BB, 256, 0, stream>>>(
        points, z_enc, Wm, bias, counts, planes, out);
}

// Round 16
// 33.819 us; speedup vs baseline: 1.3202x; 1.1654x over previous
//
#include <hip/hip_runtime.h>

#define BB 8
#define NN 2048
#define TT 64
#define DD 256
#define KK 128

// ---- per-block LDS counting-sort grid ----
#define GSZ 22
#define NC (GSZ * GSZ * GSZ)   // 10648
#define NCP (512 * 21)         // 10752: padded for the 21-cells/thread scan
#define DTHR 0.053f     // conservative per-dim candidate radius (covers fp error)
#define D2THR 0.0025f   // sqrt(max(d2,0)) < 0.05  <=>  d2 < 0.0025 (exact)

// ---------------------------------------------------------------------------
// One block per (b,t). Counting-sort LDS grid + sorted-order queries.
// Numerics bit-identical to reference (validated r2-r15):
//   d2 = (rsq + pts_sq) - dot(2r, p), non-FMA, left-assoc; d2 < 0.0025f.
// Single change vs r15 (39.4 us): GSZ 16 -> 22. r9/r10 isolated the
// candidate-scan LDS traffic as ~12 us at GSZ=16 (5.4 us per 1.45x);
// smaller cells cut candidate reads ~2.2x. h >= 0.06 > DTHR invariant holds.
// ---------------------------------------------------------------------------
__global__ __launch_bounds__(512) void detect_kernel(
    const float* __restrict__ points, const int* __restrict__ sample_idx,
    const float* __restrict__ z_local,
    int* __restrict__ counts, float* __restrict__ planes,
    float* __restrict__ out)
{
#pragma clang fp contract(off)
    __shared__ float4 sp[NN];        // 32 KB cell-sorted {x,y,z,||p||^2}
    __shared__ int    cellofs[NCP];  // 42 KB: hist -> excl start -> end offset
    __shared__ float  sred[8][6];
    __shared__ int    swsum[8];
    __shared__ float  g[6];          // org[3], h[3]
    __shared__ int    blk_cnt;

    const int tid  = threadIdx.x;
    const int lane = tid & 63;
    const int wav  = tid >> 6;
    const int bt   = blockIdx.x;
    const int b    = bt / TT;

    if (tid == 0) blk_cnt = 0;

    const float* P = points + (size_t)b * NN * 3;

    // ---- candidate plane (hoisted: loads overlap staging) ----
    const int i1 = sample_idx[bt * 2 + 0];
    const int i2 = sample_idx[bt * 2 + 1];
    const float q1x = P[i1 * 3 + 0], q1y = P[i1 * 3 + 1], q1z = P[i1 * 3 + 2];
    const float q2x = P[i2 * 3 + 0], q2y = P[i2 * 3 + 1], q2z = P[i2 * 3 + 2];
    const float dx0 = q2x - q1x, dy0 = q2y - q1y, dz0 = q2z - q1z;
    const float nd  = sqrtf((dx0 * dx0 + dy0 * dy0) + dz0 * dz0);
    const float den = nd + 1e-12f;
    const float nx = dx0 / den, ny = dy0 / den, nz = dz0 / den;
    const float e0 = (nx * (q1x + q2x)) * 0.5f;
    const float e1 = (ny * (q1y + q2y)) * 0.5f;
    const float e2 = (nz * (q1z + q2z)) * 0.5f;
    const float off = (e0 + e1) + e2;
    const float nnorm = sqrtf((nx * nx + ny * ny) + nz * nz);
    const float nden  = nnorm + 1e-12f;
    const float nnx = nx / nden, nny = ny / nden, nnz = nz / nden;

    // z_local passthrough slice: 65536 float4 total / 512 blocks = 128 each
    if (tid < 128) {
        const float4* zl = (const float4*)z_local;
        float4* zo = (float4*)(out + BB * DD);
        zo[bt * 128 + tid] = zl[bt * 128 + tid];
    }

    // ---- load 4 points/thread to registers + bbox ----
    float px[4], py[4], pz[4], ps[4];
    float mnx = 3.4e38f, mny = 3.4e38f, mnz = 3.4e38f;
    float mxx = -3.4e38f, mxy = -3.4e38f, mxz = -3.4e38f;
#pragma unroll
    for (int k = 0; k < 4; ++k) {
        const int j = tid + k * 512;
        const float x = P[j * 3 + 0], y = P[j * 3 + 1], z = P[j * 3 + 2];
        px[k] = x; py[k] = y; pz[k] = z;
        ps[k] = (x * x + y * y) + z * z;   // matches pts_sq op order
        mnx = fminf(mnx, x); mxx = fmaxf(mxx, x);
        mny = fminf(mny, y); mxy = fmaxf(mxy, y);
        mnz = fminf(mnz, z); mxz = fmaxf(mxz, z);
    }
#pragma unroll
    for (int o = 32; o > 0; o >>= 1) {
        mnx = fminf(mnx, __shfl_xor(mnx, o));
        mny = fminf(mny, __shfl_xor(mny, o));
        mnz = fminf(mnz, __shfl_xor(mnz, o));
        mxx = fmaxf(mxx, __shfl_xor(mxx, o));
        mxy = fmaxf(mxy, __shfl_xor(mxy, o));
        mxz = fmaxf(mxz, __shfl_xor(mxz, o));
    }
    if (lane == 0) {
        sred[wav][0] = mnx; sred[wav][1] = mny; sred[wav][2] = mnz;
        sred[wav][3] = mxx; sred[wav][4] = mxy; sred[wav][5] = mxz;
    }
    // zero histogram (padding included; independent of the reduction)
    for (int c = tid; c < NCP; c += 512) cellofs[c] = 0;
    __syncthreads();

    if (tid == 0) {
        float a0 = sred[0][0], a1 = sred[0][1], a2 = sred[0][2];
        float m3 = sred[0][3], m4 = sred[0][4], m5 = sred[0][5];
        for (int w = 1; w < 8; ++w) {
            a0 = fminf(a0, sred[w][0]); a1 = fminf(a1, sred[w][1]); a2 = fminf(a2, sred[w][2]);
            m3 = fmaxf(m3, sred[w][3]); m4 = fmaxf(m4, sred[w][4]); m5 = fmaxf(m5, sred[w][5]);
        }
        g[0] = a0 - 1e-3f; g[1] = a1 - 1e-3f; g[2] = a2 - 1e-3f;
        g[3] = fmaxf((m3 - g[0]) * (1.0f / 21.9f), 0.06f);
        g[4] = fmaxf((m4 - g[1]) * (1.0f / 21.9f), 0.06f);
        g[5] = fmaxf((m5 - g[2]) * (1.0f / 21.9f), 0.06f);
    }
    __syncthreads();
    const float ogx = g[0], ogy = g[1], ogz = g[2];
    const float hx = g[3], hy = g[4], hz = g[5];
    const float ivx = 1.0f / hx, ivy = 1.0f / hy, ivz = 1.0f / hz;

    // ---- histogram ----
    int cell[4];
#pragma unroll
    for (int k = 0; k < 4; ++k) {
        int cx = (int)floorf((px[k] - ogx) * ivx);
        int cy = (int)floorf((py[k] - ogy) * ivy);
        int cz = (int)floorf((pz[k] - ogz) * ivz);
        cx = min(GSZ - 1, max(0, cx));
        cy = min(GSZ - 1, max(0, cy));
        cz = min(GSZ - 1, max(0, cz));
        cell[k] = (cz * GSZ + cy) * GSZ + cx;
        atomicAdd(&cellofs[cell[k]], 1);
    }
    __syncthreads();

    // ---- exclusive prefix sum over NCP=10752 cells (21 per thread) ----
    const int base = tid * 21;
    int loc[21];
    int tsum = 0;
#pragma unroll
    for (int k = 0; k < 21; ++k) {
        loc[k] = tsum;                 // thread-local exclusive
        tsum += cellofs[base + k];
    }
    int inc = tsum;                    // inclusive wave scan of thread sums
#pragma unroll
    for (int o = 1; o < 64; o <<= 1) {
        const int v = __shfl_up(inc, o);
        if (lane >= o) inc += v;
    }
    if (lane == 63) swsum[wav] = inc;
    __syncthreads();
    // redundant per-thread prefix over the 8 wave totals (saves a barrier)
    int wbase = 0;
    for (int w = 0; w < wav; ++w) wbase += swsum[w];
    const int texcl = (inc - tsum) + wbase;   // exclusive over threads
#pragma unroll
    for (int k = 0; k < 21; ++k) cellofs[base + k] = texcl + loc[k];  // excl starts
    __syncthreads();

    // ---- scatter: cellofs[c] becomes END offset after all inserts ----
#pragma unroll
    for (int k = 0; k < 4; ++k) {
        const int pos = atomicAdd(&cellofs[cell[k]], 1);
        sp[pos] = make_float4(px[k], py[k], pz[k], ps[k]);
    }
    __syncthreads();   // sorted grid complete

    // ---- queries in SORTED order: reflect + range-scan exact NN match ----
    int cnt = 0;
#pragma unroll
    for (int k = 0; k < 4; ++k) {
        const int n = tid + k * 512;
        const float4 q = sp[n];        // sorted: adjacent lanes share cells
        const float sd = ((q.x * nnx + q.y * nny) + q.z * nnz) - off;
        const float s  = 2.0f * sd;
        const float rx = q.x - s * nnx;
        const float ry = q.y - s * nny;
        const float rz = q.z - s * nnz;
        const float rsq = (rx * rx + ry * ry) + rz * rz;
        const float r2x = rx + rx, r2y = ry + ry, r2z = rz + rz; // exact *2

        const float tx = rx - ogx; const float cfx = floorf(tx * ivx);
        const float ty = ry - ogy; const float cfy = floorf(ty * ivy);
        const float tz = rz - ogz; const float cfz = floorf(tz * ivz);
        const int cxi = (int)cfx, cyi = (int)cfy, czi = (int)cfz;
        const float fx = tx - cfx * hx;
        const float fy = ty - cfy * hy;
        const float fz = tz - cfz * hz;
        // x-window as one contiguous cell-index range
        const int cx0 = max(0, cxi + ((fx < DTHR) ? -1 : 0));
        const int cx1 = min(GSZ - 1, cxi + ((fx > hx - DTHR) ? 1 : 0));
        const int ly = (fy < DTHR) ? -1 : 0, uy = (fy > hy - DTHR) ? 1 : 0;
        const int lz = (fz < DTHR) ? -1 : 0, uz = (fz > hz - DTHR) ? 1 : 0;

        int matched = 0;
        if (cx0 <= cx1) {
            for (int dz = lz; dz <= uz; ++dz) {
                const int cz = czi + dz; if ((unsigned)cz >= GSZ) continue;
                for (int dy = ly; dy <= uy; ++dy) {
                    const int cy = cyi + dy; if ((unsigned)cy >= GSZ) continue;
                    const int rowbase = (cz * GSZ + cy) * GSZ;
                    const int idx0 = rowbase + cx0;
                    const int idx1 = rowbase + cx1;
                    const int jb = (idx0 == 0) ? 0 : cellofs[idx0 - 1];
                    const int je = cellofs[idx1];
                    for (int j = jb; j < je; ++j) {
                        const float4 pm = sp[j];
                        const float c2 = (r2x * pm.x + r2y * pm.y) + r2z * pm.z;
                        const float t1 = rsq + pm.w;
                        matched |= ((t1 - c2) < D2THR) ? 1 : 0;
                    }
                }
            }
        }
        cnt += matched;
    }

    for (int o = 32; o > 0; o >>= 1) cnt += __shfl_down(cnt, o);
    if (lane == 0) atomicAdd(&blk_cnt, cnt);
    __syncthreads();

    if (tid == 0) {
        counts[bt] = blk_cnt;
        planes[bt * 5 + 0] = nx;
        planes[bt * 5 + 1] = ny;
        planes[bt * 5 + 2] = nz;
        planes[bt * 5 + 3] = off;
        planes[bt * 5 + 4] = nd;
    }
}

// ---------------------------------------------------------------------------
// Kernel 2: per-batch finalize:
//   wave 0: 64 lanes load (count, plane) in ONE latency round; exact argmax
//           (frac = count/2048 exact; max + first-wins via ballot/ffs; winner
//            fields broadcast via shfl).
//   all waves: centroid via shfl partials. Then GEMV.
// ---------------------------------------------------------------------------
__global__ __launch_bounds__(256) void finalize_kernel(
    const float* __restrict__ points, const float* __restrict__ z_enc,
    const float* __restrict__ Wm, const float* __restrict__ bias,
    const int* __restrict__ counts, const float* __restrict__ planes,
    float* __restrict__ out)
{
    const int b = blockIdx.x, tid = threadIdx.x;
    const int lane = tid & 63, wav = tid >> 6;
    __shared__ float zaug[DD + 4];
    __shared__ float swc[4][3];
    __shared__ float sbest[5];

    // centroid partials: 8 pts per thread, wave shfl reduce
    const float* P = points + (size_t)b * NN * 3;
    float sx = 0.f, sy = 0.f, sz = 0.f;
#pragma unroll
    for (int k = 0; k < 8; ++k) {
        const int j = tid + k * 256;
        sx += P[j * 3 + 0]; sy += P[j * 3 + 1]; sz += P[j * 3 + 2];
    }
#pragma unroll
    for (int o = 32; o > 0; o >>= 1) {
        sx += __shfl_xor(sx, o); sy += __shfl_xor(sy, o); sz += __shfl_xor(sz, o);
    }
    if (lane == 0) { swc[wav][0] = sx; swc[wav][1] = sy; swc[wav][2] = sz; }

    zaug[tid] = z_enc[b * DD + tid];

    // wave 0: parallel argmax over the 64 candidates
    if (wav == 0) {
        const int bt = b * TT + lane;
        const float p0 = planes[bt * 5 + 0];
        const float p1 = planes[bt * 5 + 1];
        const float p2 = planes[bt * 5 + 2];
        const float p3 = planes[bt * 5 + 3];
        const float ndv = planes[bt * 5 + 4];
        const int   c  = counts[bt];
        // frac exact: count*(1/2048) with count <= 2^11 -> exact float
        const float frac = (ndv < 1e-8f) ? -1.0f : (float)c * (1.0f / 2048.0f);
        float m = frac;
#pragma unroll
        for (int o = 32; o > 0; o >>= 1) m = fmaxf(m, __shfl_xor(m, o));
        const unsigned long long win = __ballot(frac == m);
        const int first = __ffsll(win) - 1;   // smallest t among maxima
        const float w0 = __shfl(p0, first);
        const float w1 = __shfl(p1, first);
        const float w2 = __shfl(p2, first);
        const float w3 = __shfl(p3, first);
        if (lane == 0) {
            if (m > 0.0f) {
                sbest[0] = w0; sbest[1] = w1; sbest[2] = w2; sbest[3] = w3; sbest[4] = m;
            } else {
                sbest[0] = 0.f; sbest[1] = 1.f; sbest[2] = 0.f; sbest[3] = 0.f; sbest[4] = 0.f;
            }
        }
    }
    __syncthreads();

    if (tid == 0) {
        const float cx = (((swc[0][0] + swc[1][0]) + swc[2][0]) + swc[3][0]) / (float)NN;
        const float cy = (((swc[0][1] + swc[1][1]) + swc[2][1]) + swc[3][1]) / (float)NN;
        const float cz = (((swc[0][2] + swc[1][2]) + swc[2][2]) + swc[3][2]) / (float)NN;
        const float bn0 = sbest[0], bn1 = sbest[1], bn2 = sbest[2];
        const float bo = sbest[3], bc = sbest[4];
        const float sd = ((bn0 * cx + bn1 * cy) + bn2 * cz) - bo;
        zaug[DD + 0] = bn0; zaug[DD + 1] = bn1; zaug[DD + 2] = bn2; zaug[DD + 3] = sd;
        float* normals = out + (BB * DD + BB * KK * DD);
        normals[b * 3 + 0] = bn0; normals[b * 3 + 1] = bn1; normals[b * 3 + 2] = bn2;
        float* offs = normals + BB * 3;
        offs[b] = bo;
        float* conf = offs + BB;
        conf[b] = bc;
    }
    __syncthreads();

    // GEMV: out[b][d] = bias[d] + sum_j zaug[j] * W[d][j]
    const float* wrow = Wm + (size_t)tid * (DD + 4);
    float acc = bias[tid];
    for (int j = 0; j < DD + 4; ++j) acc += zaug[j] * wrow[j];
    out[b * DD + tid] = acc;
}

extern "C" void kernel_launch(void* const* d_in, const int* in_sizes, int n_in,
                              void* d_out, int out_size, void* d_ws, size_t ws_size,
                              hipStream_t stream) {
    const float* points     = (const float*)d_in[0];
    const float* z_enc      = (const float*)d_in[1];
    const float* z_local    = (const float*)d_in[2];
    // d_in[3] = proxy_coords (unused by reference outputs)
    const int*   sample_idx = (const int*)d_in[4];
    const float* Wm         = (const float*)d_in[5];
    const float* bias       = (const float*)d_in[6];
    float* out = (float*)d_out;

    char* wsb = (char*)d_ws;
    int*   counts = (int*)(wsb + 0);                 // BB*TT ints
    float* planes = (float*)(wsb + BB * TT * 4);     // BB*TT*5 floats

    detect_kernel<<<BB * TT, 512, 0, stream>>>(
        points, sample_idx, z_local, counts, planes, out);
    finalize_kernel<<<BB, 256, 0, stream>>>(
        points, z_enc, Wm, bias, counts, planes, out);
}

// Round 17
// 31.110 us; speedup vs baseline: 1.4352x; 1.0871x over previous
//
#include <hip/hip_runtime.h>

#define BB 8
#define NN 2048
#define TT 64
#define DD 256
#define KK 128

// ---- per-block LDS counting-sort grid, u16-packed offsets ----
#define GSZ 28
#define NC (GSZ * GSZ * GSZ)    // 21952 cells (halfwords)
#define NCI (NC / 2)            // 10976 ints
#define NCPI (512 * 22)         // 11264 ints (padded for 22 ints/thread scan)
#define DTHR 0.053f     // conservative per-dim candidate radius (covers fp error)
#define D2THR 0.0025f   // sqrt(max(d2,0)) < 0.05  <=>  d2 < 0.0025 (exact)

// ---------------------------------------------------------------------------
// One block per (b,t). Counting-sort LDS grid + sorted-order queries.
// Numerics bit-identical to reference (validated r2-r16):
//   d2 = (rsq + pts_sq) - dot(2r, p), non-FMA, left-assoc; d2 < 0.0025f.
// vs r16 (33.8 us): GSZ 22 -> 28 with u16-PACKED cell table (counts <= 2048
// so halfword atomicAdd never carries). Scan-volume model (validated across
// GSZ 14/16/22 at ~90 us per (h+2d)^3) predicts ~2.8 us saved.
// LDS 32+44 = 76 KB -> still 2 blocks/CU.
// ---------------------------------------------------------------------------
__global__ __launch_bounds__(512) void detect_kernel(
    const float* __restrict__ points, const int* __restrict__ sample_idx,
    const float* __restrict__ z_local,
    int* __restrict__ counts, float* __restrict__ planes,
    float* __restrict__ out)
{
#pragma clang fp contract(off)
    __shared__ float4 sp[NN];         // 32 KB cell-sorted {x,y,z,||p||^2}
    __shared__ unsigned int cellofs[NCPI]; // 44 KB: u16-pair hist/starts/ends
    __shared__ float  sred[8][6];
    __shared__ int    swsum[8];
    __shared__ float  g[6];           // org[3], h[3]
    __shared__ int    blk_cnt;

    const int tid  = threadIdx.x;
    const int lane = tid & 63;
    const int wav  = tid >> 6;
    const int bt   = blockIdx.x;
    const int b    = bt / TT;

    if (tid == 0) blk_cnt = 0;

    const float* P = points + (size_t)b * NN * 3;

    // ---- candidate plane (hoisted: loads overlap staging) ----
    const int i1 = sample_idx[bt * 2 + 0];
    const int i2 = sample_idx[bt * 2 + 1];
    const float q1x = P[i1 * 3 + 0], q1y = P[i1 * 3 + 1], q1z = P[i1 * 3 + 2];
    const float q2x = P[i2 * 3 + 0], q2y = P[i2 * 3 + 1], q2z = P[i2 * 3 + 2];
    const float dx0 = q2x - q1x, dy0 = q2y - q1y, dz0 = q2z - q1z;
    const float nd  = sqrtf((dx0 * dx0 + dy0 * dy0) + dz0 * dz0);
    const float den = nd + 1e-12f;
    const float nx = dx0 / den, ny = dy0 / den, nz = dz0 / den;
    const float e0 = (nx * (q1x + q2x)) * 0.5f;
    const float e1 = (ny * (q1y + q2y)) * 0.5f;
    const float e2 = (nz * (q1z + q2z)) * 0.5f;
    const float off = (e0 + e1) + e2;
    const float nnorm = sqrtf((nx * nx + ny * ny) + nz * nz);
    const float nden  = nnorm + 1e-12f;
    const float nnx = nx / nden, nny = ny / nden, nnz = nz / nden;

    // z_local passthrough slice: 65536 float4 total / 512 blocks = 128 each
    if (tid < 128) {
        const float4* zl = (const float4*)z_local;
        float4* zo = (float4*)(out + BB * DD);
        zo[bt * 128 + tid] = zl[bt * 128 + tid];
    }

    // ---- load 4 points/thread to registers + bbox ----
    float px[4], py[4], pz[4], ps[4];
    float mnx = 3.4e38f, mny = 3.4e38f, mnz = 3.4e38f;
    float mxx = -3.4e38f, mxy = -3.4e38f, mxz = -3.4e38f;
#pragma unroll
    for (int k = 0; k < 4; ++k) {
        const int j = tid + k * 512;
        const float x = P[j * 3 + 0], y = P[j * 3 + 1], z = P[j * 3 + 2];
        px[k] = x; py[k] = y; pz[k] = z;
        ps[k] = (x * x + y * y) + z * z;   // matches pts_sq op order
        mnx = fminf(mnx, x); mxx = fmaxf(mxx, x);
        mny = fminf(mny, y); mxy = fmaxf(mxy, y);
        mnz = fminf(mnz, z); mxz = fmaxf(mxz, z);
    }
#pragma unroll
    for (int o = 32; o > 0; o >>= 1) {
        mnx = fminf(mnx, __shfl_xor(mnx, o));
        mny = fminf(mny, __shfl_xor(mny, o));
        mnz = fminf(mnz, __shfl_xor(mnz, o));
        mxx = fmaxf(mxx, __shfl_xor(mxx, o));
        mxy = fmaxf(mxy, __shfl_xor(mxy, o));
        mxz = fmaxf(mxz, __shfl_xor(mxz, o));
    }
    if (lane == 0) {
        sred[wav][0] = mnx; sred[wav][1] = mny; sred[wav][2] = mnz;
        sred[wav][3] = mxx; sred[wav][4] = mxy; sred[wav][5] = mxz;
    }
    // zero histogram (padding included; independent of the reduction)
    for (int c = tid; c < NCPI; c += 512) cellofs[c] = 0u;
    __syncthreads();

    if (tid == 0) {
        float a0 = sred[0][0], a1 = sred[0][1], a2 = sred[0][2];
        float m3 = sred[0][3], m4 = sred[0][4], m5 = sred[0][5];
        for (int w = 1; w < 8; ++w) {
            a0 = fminf(a0, sred[w][0]); a1 = fminf(a1, sred[w][1]); a2 = fminf(a2, sred[w][2]);
            m3 = fmaxf(m3, sred[w][3]); m4 = fmaxf(m4, sred[w][4]); m5 = fmaxf(m5, sred[w][5]);
        }
        g[0] = a0 - 1e-3f; g[1] = a1 - 1e-3f; g[2] = a2 - 1e-3f;
        g[3] = fmaxf((m3 - g[0]) * (1.0f / 27.9f), 0.06f);
        g[4] = fmaxf((m4 - g[1]) * (1.0f / 27.9f), 0.06f);
        g[5] = fmaxf((m5 - g[2]) * (1.0f / 27.9f), 0.06f);
    }
    __syncthreads();
    const float ogx = g[0], ogy = g[1], ogz = g[2];
    const float hx = g[3], hy = g[4], hz = g[5];
    const float ivx = 1.0f / hx, ivy = 1.0f / hy, ivz = 1.0f / hz;

    // ---- histogram (u16-packed: counts <= 2048 -> no carry) ----
    int cell[4];
#pragma unroll
    for (int k = 0; k < 4; ++k) {
        int cx = (int)floorf((px[k] - ogx) * ivx);
        int cy = (int)floorf((py[k] - ogy) * ivy);
        int cz = (int)floorf((pz[k] - ogz) * ivz);
        cx = min(GSZ - 1, max(0, cx));
        cy = min(GSZ - 1, max(0, cy));
        cz = min(GSZ - 1, max(0, cz));
        cell[k] = (cz * GSZ + cy) * GSZ + cx;
        atomicAdd(&cellofs[cell[k] >> 1], 1u << ((cell[k] & 1) * 16));
    }
    __syncthreads();

    // ---- exclusive prefix sum over 22528 halfwords (44 per thread, 2-pass) --
    const int base = tid * 22;
    int tsum = 0;
#pragma unroll
    for (int k = 0; k < 22; ++k) {
        const unsigned int u = cellofs[base + k];
        tsum += (int)(u & 0xFFFFu) + (int)(u >> 16);
    }
    int inc = tsum;                    // inclusive wave scan of thread sums
#pragma unroll
    for (int o = 1; o < 64; o <<= 1) {
        const int v = __shfl_up(inc, o);
        if (lane >= o) inc += v;
    }
    if (lane == 63) swsum[wav] = inc;
    __syncthreads();
    // redundant per-thread prefix over the 8 wave totals (saves a barrier)
    int wbase = 0;
    for (int w = 0; w < wav; ++w) wbase += swsum[w];
    int run = (inc - tsum) + wbase;    // exclusive over threads
#pragma unroll
    for (int k = 0; k < 22; ++k) {     // write back packed exclusive starts
        const unsigned int u = cellofs[base + k];
        const int lo = (int)(u & 0xFFFFu), hi = (int)(u >> 16);
        cellofs[base + k] = (unsigned int)run | ((unsigned int)(run + lo) << 16);
        run += lo + hi;
    }
    __syncthreads();

    // ---- scatter: packed halfword becomes END offset after all inserts ----
#pragma unroll
    for (int k = 0; k < 4; ++k) {
        const int sh = (cell[k] & 1) * 16;
        const unsigned int old = atomicAdd(&cellofs[cell[k] >> 1], 1u << sh);
        const int pos = (int)((old >> sh) & 0xFFFFu);
        sp[pos] = make_float4(px[k], py[k], pz[k], ps[k]);
    }
    __syncthreads();   // sorted grid complete

    // ---- queries in SORTED order: reflect + range-scan exact NN match ----
    const unsigned short* co16 = (const unsigned short*)cellofs;
    int cnt = 0;
#pragma unroll
    for (int k = 0; k < 4; ++k) {
        const int n = tid + k * 512;
        const float4 q = sp[n];        // sorted: adjacent lanes share cells
        const float sd = ((q.x * nnx + q.y * nny) + q.z * nnz) - off;
        const float s  = 2.0f * sd;
        const float rx = q.x - s * nnx;
        const float ry = q.y - s * nny;
        const float rz = q.z - s * nnz;
        const float rsq = (rx * rx + ry * ry) + rz * rz;
        const float r2x = rx + rx, r2y = ry + ry, r2z = rz + rz; // exact *2

        const float tx = rx - ogx; const float cfx = floorf(tx * ivx);
        const float ty = ry - ogy; const float cfy = floorf(ty * ivy);
        const float tz = rz - ogz; const float cfz = floorf(tz * ivz);
        const int cxi = (int)cfx, cyi = (int)cfy, czi = (int)cfz;
        const float fx = tx - cfx * hx;
        const float fy = ty - cfy * hy;
        const float fz = tz - cfz * hz;
        // x-window as one contiguous cell-index range
        const int cx0 = max(0, cxi + ((fx < DTHR) ? -1 : 0));
        const int cx1 = min(GSZ - 1, cxi + ((fx > hx - DTHR) ? 1 : 0));
        const int ly = (fy < DTHR) ? -1 : 0, uy = (fy > hy - DTHR) ? 1 : 0;
        const int lz = (fz < DTHR) ? -1 : 0, uz = (fz > hz - DTHR) ? 1 : 0;

        int matched = 0;
        if (cx0 <= cx1) {
            for (int dz = lz; dz <= uz; ++dz) {
                const int cz = czi + dz; if ((unsigned)cz >= GSZ) continue;
                for (int dy = ly; dy <= uy; ++dy) {
                    const int cy = cyi + dy; if ((unsigned)cy >= GSZ) continue;
                    const int rowbase = (cz * GSZ + cy) * GSZ;
                    const int idx0 = rowbase + cx0;
                    const int idx1 = rowbase + cx1;
                    const int jb = (idx0 == 0) ? 0 : (int)co16[idx0 - 1];
                    const int je = (int)co16[idx1];
                    for (int j = jb; j < je; ++j) {
                        const float4 pm = sp[j];
                        const float c2 = (r2x * pm.x + r2y * pm.y) + r2z * pm.z;
                        const float t1 = rsq + pm.w;
                        matched |= ((t1 - c2) < D2THR) ? 1 : 0;
                    }
                }
            }
        }
        cnt += matched;
    }

    for (int o = 32; o > 0; o >>= 1) cnt += __shfl_down(cnt, o);
    if (lane == 0) atomicAdd(&blk_cnt, cnt);
    __syncthreads();

    if (tid == 0) {
        counts[bt] = blk_cnt;
        planes[bt * 5 + 0] = nx;
        planes[bt * 5 + 1] = ny;
        planes[bt * 5 + 2] = nz;
        planes[bt * 5 + 3] = off;
        planes[bt * 5 + 4] = nd;
    }
}

// ---------------------------------------------------------------------------
// Kernel 2: per-batch finalize:
//   wave 0: 64 lanes load (count, plane) in ONE latency round; exact argmax
//           (frac = count/2048 exact; max + first-wins via ballot/ffs; winner
//            fields broadcast via shfl).
//   all waves: centroid via shfl partials. Then GEMV.
// ---------------------------------------------------------------------------
__global__ __launch_bounds__(256) void finalize_kernel(
    const float* __restrict__ points, const float* __restrict__ z_enc,
    const float* __restrict__ Wm, const float* __restrict__ bias,
    const int* __restrict__ counts, const float* __restrict__ planes,
    float* __restrict__ out)
{
    const int b = blockIdx.x, tid = threadIdx.x;
    const int lane = tid & 63, wav = tid >> 6;
    __shared__ float zaug[DD + 4];
    __shared__ float swc[4][3];
    __shared__ float sbest[5];

    // centroid partials: 8 pts per thread, wave shfl reduce
    const float* P = points + (size_t)b * NN * 3;
    float sx = 0.f, sy = 0.f, sz = 0.f;
#pragma unroll
    for (int k = 0; k < 8; ++k) {
        const int j = tid + k * 256;
        sx += P[j * 3 + 0]; sy += P[j * 3 + 1]; sz += P[j * 3 + 2];
    }
#pragma unroll
    for (int o = 32; o > 0; o >>= 1) {
        sx += __shfl_xor(sx, o); sy += __shfl_xor(sy, o); sz += __shfl_xor(sz, o);
    }
    if (lane == 0) { swc[wav][0] = sx; swc[wav][1] = sy; swc[wav][2] = sz; }

    zaug[tid] = z_enc[b * DD + tid];

    // wave 0: parallel argmax over the 64 candidates
    if (wav == 0) {
        const int bt = b * TT + lane;
        const float p0 = planes[bt * 5 + 0];
        const float p1 = planes[bt * 5 + 1];
        const float p2 = planes[bt * 5 + 2];
        const float p3 = planes[bt * 5 + 3];
        const float ndv = planes[bt * 5 + 4];
        const int   c  = counts[bt];
        // frac exact: count*(1/2048) with count <= 2^11 -> exact float
        const float frac = (ndv < 1e-8f) ? -1.0f : (float)c * (1.0f / 2048.0f);
        float m = frac;
#pragma unroll
        for (int o = 32; o > 0; o >>= 1) m = fmaxf(m, __shfl_xor(m, o));
        const unsigned long long win = __ballot(frac == m);
        const int first = __ffsll(win) - 1;   // smallest t among maxima
        const float w0 = __shfl(p0, first);
        const float w1 = __shfl(p1, first);
        const float w2 = __shfl(p2, first);
        const float w3 = __shfl(p3, first);
        if (lane == 0) {
            if (m > 0.0f) {
                sbest[0] = w0; sbest[1] = w1; sbest[2] = w2; sbest[3] = w3; sbest[4] = m;
            } else {
                sbest[0] = 0.f; sbest[1] = 1.f; sbest[2] = 0.f; sbest[3] = 0.f; sbest[4] = 0.f;
            }
        }
    }
    __syncthreads();

    if (tid == 0) {
        const float cx = (((swc[0][0] + swc[1][0]) + swc[2][0]) + swc[3][0]) / (float)NN;
        const float cy = (((swc[0][1] + swc[1][1]) + swc[2][1]) + swc[3][1]) / (float)NN;
        const float cz = (((swc[0][2] + swc[1][2]) + swc[2][2]) + swc[3][2]) / (float)NN;
        const float bn0 = sbest[0], bn1 = sbest[1], bn2 = sbest[2];
        const float bo = sbest[3], bc = sbest[4];
        const float sd = ((bn0 * cx + bn1 * cy) + bn2 * cz) - bo;
        zaug[DD + 0] = bn0; zaug[DD + 1] = bn1; zaug[DD + 2] = bn2; zaug[DD + 3] = sd;
        float* normals = out + (BB * DD + BB * KK * DD);
        normals[b * 3 + 0] = bn0; normals[b * 3 + 1] = bn1; normals[b * 3 + 2] = bn2;
        float* offs = normals + BB * 3;
        offs[b] = bo;
        float* conf = offs + BB;
        conf[b] = bc;
    }
    __syncthreads();

    // GEMV: out[b][d] = bias[d] + sum_j zaug[j] * W[d][j]
    const float* wrow = Wm + (size_t)tid * (DD + 4);
    float acc = bias[tid];
    for (int j = 0; j < DD + 4; ++j) acc += zaug[j] * wrow[j];
    out[b * DD + tid] = acc;
}

extern "C" void kernel_launch(void* const* d_in, const int* in_sizes, int n_in,
                              void* d_out, int out_size, void* d_ws, size_t ws_size,
                              hipStream_t stream) {
    const float* points     = (const float*)d_in[0];
    const float* z_enc      = (const float*)d_in[1];
    const float* z_local    = (const float*)d_in[2];
    // d_in[3] = proxy_coords (unused by reference outputs)
    const int*   sample_idx = (const int*)d_in[4];
    const float* Wm         = (const float*)d_in[5];
    const float* bias       = (const float*)d_in[6];
    float* out = (float*)d_out;

    char* wsb = (char*)d_ws;
    int*   counts = (int*)(wsb + 0);                 // BB*TT ints
    float* planes = (float*)(wsb + BB * TT * 4);     // BB*TT*5 floats

    detect_kernel<<<BB * TT, 512, 0, stream>>>(
        points, sample_idx, z_local, counts, planes, out);
    finalize_kernel<<<BB, 256, 0, stream>>>(
        points, z_enc, Wm, bias, counts, planes, out);
}